// Round 19
// baseline (351.442 us; speedup 1.0000x reference)
//
#include <hip/hip_runtime.h>
#include <hip/hip_fp16.h>
#include <math.h>

#define TPB 256
#define PMAX 128       // max partitions
#define PSH 10         // partition = dst >> 10 (1024 nodes/partition; n <= 131072)
#define PW  1024       // nodes per partition
#define CHUNK 2048     // edges per block in scatter; KPT = CHUNK/TPB = 8
#define KPT 8
#define PCAP 38912     // per-partition staging cap (mean ~33.8K, sigma ~180 -> +28 sigma)
#define PCSTR 16       // pcursor stride: 1 counter per 64B cache line

__device__ __forceinline__ float leaky02(float x) { return x > 0.f ? x : 0.2f * x; }
__device__ __forceinline__ float eluf(float x) { return x > 0.f ? x : (__expf(x) - 1.f); }

// ====================== CSR build (direct-write scatter -> finalize w/ inline scan) ======================

__global__ __launch_bounds__(256) void scatter_kernel(const int* __restrict__ src,
                                                      const int* __restrict__ dst,
                                                      int E, int n,
                                                      int* __restrict__ pcursor,
                                                      unsigned* __restrict__ pstage) {
  __shared__ int lcnt[4][PMAX];    // per-wave counts -> per-wave cursors
  __shared__ int lbase[PMAX];      // global base (pcursor)
  int t = threadIdx.x;
  int wid = t >> 6;
  int Etot = E + n;
  int c0 = blockIdx.x * CHUNK;
  if (c0 >= Etot) return;
  int c1 = min(c0 + CHUNK, Etot);
  for (int j = t; j < 4 * PMAX; j += TPB) ((int*)lcnt)[j] = 0;

  int dd[KPT], ss[KPT];
  bool vv[KPT];
#pragma unroll
  for (int k = 0; k < KPT; ++k) {
    int idx = c0 + t + k * TPB;
    vv[k] = idx < c1;
    if (vv[k]) {
      if (idx < E) { ss[k] = src[idx]; dd[k] = dst[idx]; }
      else         { ss[k] = dd[k] = idx - E; }
    } else { ss[k] = 0; dd[k] = 0; }
  }
  __syncthreads();
#pragma unroll
  for (int k = 0; k < KPT; ++k)
    if (vv[k]) atomicAdd(&lcnt[wid][dd[k] >> PSH], 1);
  __syncthreads();
  if (t < PMAX) {
    int a0 = lcnt[0][t], a1 = lcnt[1][t], a2 = lcnt[2][t], a3 = lcnt[3][t];
    int tot = a0 + a1 + a2 + a3;
    lcnt[0][t] = 0; lcnt[1][t] = a0; lcnt[2][t] = a0 + a1; lcnt[3][t] = a0 + a1 + a2;
    lbase[t] = tot ? atomicAdd(&pcursor[t * PCSTR], tot) : 0;
  }
  __syncthreads();
#pragma unroll
  for (int k = 0; k < KPT; ++k) {
    if (vv[k]) {
      int p = dd[k] >> PSH;
      int sub = atomicAdd(&lcnt[wid][p], 1);   // starts at wave's exclusive offset
      pstage[(size_t)p * PCAP + lbase[p] + sub] =
          ((unsigned)ss[k] << PSH) | (unsigned)(dd[k] & (PW - 1));
    }
  }
}

// One 1024-thread block per partition. Inline 128-wide scan of padded pcursor
// totals; shfl-based node scan; streaming passes batched x4.
__global__ __launch_bounds__(1024) void build_csr_kernel(const unsigned* __restrict__ pstage,
                                                         const int* __restrict__ pcursor,
                                                         int nvtx,
                                                         int* __restrict__ rowptr,
                                                         int* __restrict__ csr_src) {
  __shared__ int ssum[PMAX];
  __shared__ int lhist[PW];
  __shared__ int lcur[PW];
  int t = threadIdx.x;
  int lane = t & 63;
  int wid = t >> 6;
  int p = blockIdx.x;
  size_t rbase = (size_t)p * PCAP;
  if (t < PMAX) ssum[t] = pcursor[t * PCSTR];
  lhist[t] = 0;
  __syncthreads();
  for (int off = 1; off < PMAX; off <<= 1) {
    int a = 0;
    if (t < PMAX && t >= off) a = ssum[t - off];
    __syncthreads();
    if (t < PMAX) ssum[t] += a;
    __syncthreads();
  }
  int cnt = pcursor[p * PCSTR];
  int wbase = ssum[p] - cnt;          // exclusive prefix for this partition
  int nodebase = p << PSH;
  for (int i = t; i < cnt; i += 4096) {
    unsigned w[4]; bool vv[4];
#pragma unroll
    for (int k = 0; k < 4; ++k) {
      int j = i + k * 1024;
      vv[k] = j < cnt;
      w[k] = vv[k] ? pstage[rbase + j] : 0u;
    }
#pragma unroll
    for (int k = 0; k < 4; ++k)
      if (vv[k]) atomicAdd(&lhist[w[k] & (PW - 1)], 1);
  }
  __syncthreads();
  int v = lhist[t];
  int x = v;
#pragma unroll
  for (int off = 1; off < 64; off <<= 1) {
    int u = __shfl_up(x, off);
    if (lane >= off) x += u;
  }
  if (lane == 63) lcur[wid] = x;       // wave sums in lcur[0..15]
  __syncthreads();
  if (t < 16) {
    int wsum = lcur[t];
    int y = wsum;
#pragma unroll
    for (int off = 1; off < 16; off <<= 1) {
      int u = __shfl_up(y, off);
      if (t >= off) y += u;
    }
    lcur[t] = y - wsum;                // exclusive wave offsets
  }
  __syncthreads();
  int acc = wbase + x + lcur[wid] - v; // exclusive start position of node t
  __syncthreads();
  lcur[t] = acc;
  int node = nodebase + t;
  if (node < nvtx) rowptr[node] = acc;
  __syncthreads();
  for (int i = t; i < cnt; i += 4096) {
    unsigned w[4]; bool vv[4];
#pragma unroll
    for (int k = 0; k < 4; ++k) {
      int j = i + k * 1024;
      vv[k] = j < cnt;
      w[k] = vv[k] ? pstage[rbase + j] : 0u;
    }
#pragma unroll
    for (int k = 0; k < 4; ++k) {
      if (vv[k]) {
        int pos = atomicAdd(&lcur[w[k] & (PW - 1)], 1);
        csr_src[pos] = (int)(w[k] >> PSH);
      }
    }
  }
  if (p == (int)gridDim.x - 1 && t == 0) rowptr[nvtx] = wbase + cnt;
}

// ====================== node transform (h = x@W fp32 -> stored fp16, attn logits fp32) ======================

template<int IN, int OUT, int H>
__global__ void transform_kernel(const float* __restrict__ x, const float* __restrict__ W,
                                 const float* __restrict__ a_src, const float* __restrict__ a_dst,
                                 __half* __restrict__ h, float* __restrict__ asrc,
                                 float* __restrict__ adst, int n) {
  __shared__ float sW[IN * OUT];
  __shared__ float sa[2 * OUT];
  for (int i = threadIdx.x; i < IN * OUT; i += blockDim.x) sW[i] = W[i];
  if (threadIdx.x < OUT) {
    sa[threadIdx.x] = a_src[threadIdx.x];
    sa[OUT + threadIdx.x] = a_dst[threadIdx.x];
  }
  __syncthreads();
  int i = blockIdx.x * blockDim.x + threadIdx.x;
  if (i >= n) return;
  float xv[IN];
#pragma unroll
  for (int k = 0; k < IN; k++) xv[k] = x[(size_t)i * IN + k];
  float hv[OUT];
#pragma unroll
  for (int j = 0; j < OUT; j++) {
    float acc = 0.f;
#pragma unroll
    for (int k = 0; k < IN; k++) acc += xv[k] * sW[k * OUT + j];
    hv[j] = acc;
  }
#pragma unroll
  for (int j = 0; j < OUT; j += 2)
    ((__half2*)h)[((size_t)i * OUT + j) >> 1] = __floats2half2_rn(hv[j], hv[j + 1]);
#pragma unroll
  for (int hh = 0; hh < H; hh++) {
    float as = 0.f, ad = 0.f;
#pragma unroll
    for (int c = 0; c < 16; c++) {
      as += hv[hh * 16 + c] * sa[hh * 16 + c];
      ad += hv[hh * 16 + c] * sa[OUT + hh * 16 + c];
    }
    asrc[i * H + hh] = as;
    adst[i * H + hh] = ad;
  }
}

// ====================== gat12: 4 nodes / wave (16 lanes each) ======================
// No-max softmax (shift-invariant; R6-verified). fp16 features. 4 independent
// front-end+gather streams per wave (~32 loads in flight); window = 16 edges,
// 2 edge groups x 8 chunk slots, depth = ceil(cnt/2) <= 8. LDS quarter-window
// fully rewritten per chunk -> any NIT >= ceil(cnt/2) exact (R3-invariant).
// All shfl reductions within aligned 16-lane groups.

template<int NIT>
__device__ __forceinline__ void gat12_gather(const float2* __restrict__ sp,
                                             const uint2* __restrict__ hfp,
                                             int q, int g, float4& acc) {
  float2 p[NIT];
#pragma unroll
  for (int it = 0; it < NIT; ++it) p[it] = sp[2 * (g + it * 2)];
  uint2 hv[NIT];
#pragma unroll
  for (int it = 0; it < NIT; ++it) hv[it] = hfp[__float_as_int(p[it].x) + q];
#pragma unroll
  for (int it = 0; it < NIT; ++it) {
    float2 fa = __half22float2(*(const __half2*)&hv[it].x);
    float2 fb = __half22float2(*(const __half2*)&hv[it].y);
    float w = p[it].y;
    acc.x += w * fa.x; acc.y += w * fa.y;
    acc.z += w * fb.x; acc.w += w * fb.y;
  }
}

__device__ __forceinline__ void gat12_gather_t(const float2* sp, const uint2* hfp,
                                               int q, int g, int cnt, float4& acc) {
  switch ((cnt + 1) >> 1) {
    case 1: gat12_gather<1>(sp, hfp, q, g, acc); break;
    case 2: gat12_gather<2>(sp, hfp, q, g, acc); break;
    case 3: gat12_gather<3>(sp, hfp, q, g, acc); break;
    case 4: gat12_gather<4>(sp, hfp, q, g, acc); break;
    case 5: gat12_gather<5>(sp, hfp, q, g, acc); break;
    case 6: gat12_gather<6>(sp, hfp, q, g, acc); break;
    case 7: gat12_gather<7>(sp, hfp, q, g, acc); break;
    default: gat12_gather<8>(sp, hfp, q, g, acc); break;
  }
}

__global__ __launch_bounds__(256) void node_gat12(
    const int* __restrict__ rowptr,
    const int* __restrict__ csr_src,
    const float* __restrict__ asrc,  // [n*2] fp32
    const float* __restrict__ adst,  // [n*2] fp32
    const __half* __restrict__ hfeat,// [n*32] fp16
    const float* __restrict__ bias,  // [32]
    float* __restrict__ outb,        // [n*32] fp32
    int n) {
  __shared__ float4 s_e[4][64];    // (sidx<<3, w0, sidx<<3, w1); 16-entry window per quarter
  int t = threadIdx.x;
  int wid = t >> 6;
  int sub = t & 15;
  int quad = (t >> 4) & 3;
  int i = (blockIdx.x * TPB + t) >> 4;   // 4 nodes per wave
  if (i >= n) return;
  int start = rowptr[i];
  int d = rowptr[i + 1] - start;
  float ad0 = adst[i * 2 + 0];
  float ad1 = adst[i * 2 + 1];
  const uint2* hfp = (const uint2*)hfeat;   // 8B chunks; 8 per 32-ch row
  const float2* asrc2 = (const float2*)asrc;
  int g = sub >> 3;    // edge group 0..1
  int q = sub & 7;     // chunk slot (q<4: head0, q>=4: head1)
  const float2* sp = (const float2*)(&s_e[wid][quad * 16]) + (q >> 2);
  float4 acc = make_float4(0.f, 0.f, 0.f, 0.f);
  float sl0 = 0.f, sl1 = 0.f;

  for (int base = 0; base < d; base += 16) {
    int k = base + sub;
    int sidx8 = 0;
    float w0 = 0.f, w1 = 0.f;
    if (k < d) {
      int sidx = csr_src[start + k];
      sidx8 = sidx << 3;
      float2 av = asrc2[sidx];
      w0 = __expf(leaky02(av.x + ad0));
      w1 = __expf(leaky02(av.y + ad1));
      sl0 += w0; sl1 += w1;
    }
    s_e[wid][quad * 16 + sub] = make_float4(__int_as_float(sidx8), w0,
                                            __int_as_float(sidx8), w1);
    // same-wave LDS write->read ordering (R4-verified); tiered gather
    int cnt = min(16, d - base);
    gat12_gather_t(sp, hfp, q, g, cnt, acc);
  }

#pragma unroll
  for (int off = 8; off >= 1; off >>= 1) {
    sl0 += __shfl_xor(sl0, off);
    sl1 += __shfl_xor(sl1, off);
  }
  // reduce over 2 edge groups (g = sub>>3): xor 8 stays within the 16-lane quarter
  acc.x += __shfl_xor(acc.x, 8);  acc.y += __shfl_xor(acc.y, 8);
  acc.z += __shfl_xor(acc.z, 8);  acc.w += __shfl_xor(acc.w, 8);
  if (sub < 8) {
    float inv = 1.f / (((sub >= 4) ? sl1 : sl0) + 1e-16f);
    float4 bv = ((const float4*)bias)[sub];
    float4 o;
    o.x = eluf(acc.x * inv + bv.x);
    o.y = eluf(acc.y * inv + bv.y);
    o.z = eluf(acc.z * inv + bv.z);
    o.w = eluf(acc.w * inv + bv.w);
    ((float4*)outb)[(size_t)i * 8 + sub] = o;
  }
}

// ====================== gat3: 2 nodes / wave (unchanged from R18) ======================
template<int NIT>
__device__ __forceinline__ void gat3_gather(const float2* __restrict__ sp,
                                            const unsigned* __restrict__ hfp,
                                            int q, int g, float2& acc) {
  float2 p[NIT];
#pragma unroll
  for (int it = 0; it < NIT; ++it) p[it] = sp[g + it * 4];
  unsigned hv[NIT];
#pragma unroll
  for (int it = 0; it < NIT; ++it) hv[it] = hfp[__float_as_int(p[it].x) + q];
#pragma unroll
  for (int it = 0; it < NIT; ++it) {
    float2 f = __half22float2(*(const __half2*)&hv[it]);
    float w = p[it].y;
    acc.x += w * f.x; acc.y += w * f.y;
  }
}

__device__ __forceinline__ void gat3_gather_t(const float2* sp, const unsigned* hfp,
                                              int q, int g, int cnt, float2& acc) {
  switch ((cnt + 3) >> 2) {
    case 1: gat3_gather<1>(sp, hfp, q, g, acc); break;
    case 2: gat3_gather<2>(sp, hfp, q, g, acc); break;
    case 3: gat3_gather<3>(sp, hfp, q, g, acc); break;
    case 4: gat3_gather<4>(sp, hfp, q, g, acc); break;
    case 5: gat3_gather<5>(sp, hfp, q, g, acc); break;
    case 6: gat3_gather<6>(sp, hfp, q, g, acc); break;
    case 7: gat3_gather<7>(sp, hfp, q, g, acc); break;
    default: gat3_gather<8>(sp, hfp, q, g, acc); break;
  }
}

__global__ __launch_bounds__(256) void node_gat3(
    const int* __restrict__ rowptr,
    const int* __restrict__ csr_src,
    const float* __restrict__ asrc,  // [n] fp32
    const float* __restrict__ adst,  // [n] fp32
    const __half* __restrict__ hfeat,// [n*16] fp16
    const float* __restrict__ b3,    // [16]
    const float* __restrict__ Wout,  // [16]
    const float* __restrict__ bout,  // [1]
    float* __restrict__ out,         // [n] sigmoid ++ [n*16] embeddings (fp32)
    int n) {
  __shared__ float2 s_hw[4][64];   // (sidx<<3, w); 32-entry window per half
  int t = threadIdx.x;
  int wid = t >> 6;
  int sub = t & 31;
  int half = (t >> 5) & 1;
  int i = (blockIdx.x * TPB + t) >> 5;   // 2 nodes per wave
  if (i >= n) return;
  int start = rowptr[i];
  int d = rowptr[i + 1] - start;
  float ad0 = adst[i];
  const unsigned* hfp = (const unsigned*)hfeat;   // 4B chunks; 8 per 16-ch row
  int g = sub >> 3;    // edge group 0..3
  int q = sub & 7;     // half2 chunk slot (channels 2q, 2q+1)
  const float2* sp = &s_hw[wid][half * 32];
  float2 acc = make_float2(0.f, 0.f);
  float sl = 0.f;

  for (int base = 0; base < d; base += 32) {
    int k = base + sub;
    int sidx8 = 0;
    float w0 = 0.f;
    if (k < d) {
      int sidx = csr_src[start + k];
      sidx8 = sidx << 3;
      w0 = __expf(leaky02(asrc[sidx] + ad0));
      sl += w0;
    }
    s_hw[wid][half * 32 + sub] = make_float2(__int_as_float(sidx8), w0);
    int cnt = min(32, d - base);
    gat3_gather_t(sp, hfp, q, g, cnt, acc);
  }

#pragma unroll
  for (int off = 16; off >= 1; off >>= 1) sl += __shfl_xor(sl, off);
  acc.x += __shfl_xor(acc.x, 8);  acc.y += __shfl_xor(acc.y, 8);
  acc.x += __shfl_xor(acc.x, 16); acc.y += __shfl_xor(acc.y, 16);
  float z = 0.f;
  if (sub < 8) {
    float inv = 1.f / (sl + 1e-16f);
    float2 bv = ((const float2*)b3)[sub];
    float2 wv = ((const float2*)Wout)[sub];
    float2 o;
    o.x = eluf(acc.x * inv + bv.x);
    o.y = eluf(acc.y * inv + bv.y);
    ((float2*)(out + n))[(size_t)i * 8 + sub] = o;
    z = o.x * wv.x + o.y * wv.y;
  }
  z += __shfl_xor(z, 1);
  z += __shfl_xor(z, 2);
  z += __shfl_xor(z, 4);
  if (sub == 0) out[i] = 1.f / (1.f + __expf(-(z + bout[0])));
}

// ====================== launch ======================

extern "C" void kernel_launch(void* const* d_in, const int* in_sizes, int n_in,
                              void* d_out, int out_size, void* d_ws, size_t ws_size,
                              hipStream_t stream) {
  const float* x    = (const float*)d_in[0];
  const int*   ei   = (const int*)d_in[1];
  const float* W1   = (const float*)d_in[2];
  const float* as1  = (const float*)d_in[3];
  const float* ad1  = (const float*)d_in[4];
  const float* b1   = (const float*)d_in[5];
  const float* W2   = (const float*)d_in[6];
  const float* as2  = (const float*)d_in[7];
  const float* ad2  = (const float*)d_in[8];
  const float* b2   = (const float*)d_in[9];
  const float* W3   = (const float*)d_in[10];
  const float* as3  = (const float*)d_in[11];
  const float* ad3  = (const float*)d_in[12];
  const float* b3   = (const float*)d_in[13];
  const float* Wout = (const float*)d_in[14];
  const float* bout = (const float*)d_in[15];
  float* out = (float*)d_out;

  const int n = in_sizes[0] / 3;
  const int E = in_sizes[1] / 2;
  const int Etot = E + n;
  const int* src = ei;
  const int* dst = ei + E;
  const int nbC = (Etot + CHUNK - 1) / CHUNK;
  const int NP = ((n - 1) >> PSH) + 1;   // n=100000 -> 98 partitions

  float* ws = (float*)d_ws;
  float* bufH = ws;                               // n*32 floats (h stored as n*32 halves)
  float* bufX = bufH + (size_t)n * 32;            // n*32 fp32 (gat output / next-layer x)
  float* asrc = bufX + (size_t)n * 32;            // n*2
  float* adst = asrc + (size_t)n * 2;             // n*2
  int* rowptr  = (int*)(adst + (size_t)n * 2);    // n+1
  int* pcursor = rowptr + n + 1;                  // PMAX*PCSTR (8KB, padded)
  int* csr_src = pcursor + PMAX * PCSTR;          // Etot
  unsigned* pstage = (unsigned*)ws;               // PMAX*PCAP (~19.9MB) aliases bufH+bufX; dead before transforms
  __half* hH = (__half*)bufH;

  const int nbN = (n + TPB - 1) / TPB;
  const int nbW12 = (n + 15) / 16;                // 4 nodes per wave, 16 per block
  const int nbW3  = (n + 7) / 8;                  // 2 nodes per wave, 8 per block

  // ---- CSR build ----
  hipMemsetAsync(pcursor, 0, PMAX * PCSTR * sizeof(int), stream);
  scatter_kernel<<<nbC, TPB, 0, stream>>>(src, dst, E, n, pcursor, pstage);
  build_csr_kernel<<<NP, 1024, 0, stream>>>(pstage, pcursor, n, rowptr, csr_src);

  // ---- layer 1: in=3, out=32, H=2 ----
  transform_kernel<3, 32, 2><<<nbN, TPB, 0, stream>>>(x, W1, as1, ad1, hH, asrc, adst, n);
  node_gat12<<<nbW12, TPB, 0, stream>>>(rowptr, csr_src, asrc, adst, hH, b1, bufX, n);

  // ---- layer 2: in=32, out=32, H=2 ----
  transform_kernel<32, 32, 2><<<nbN, TPB, 0, stream>>>(bufX, W2, as2, ad2, hH, asrc, adst, n);
  node_gat12<<<nbW12, TPB, 0, stream>>>(rowptr, csr_src, asrc, adst, hH, b2, bufX, n);

  // ---- layer 3: in=32, out=16, H=1 ----
  transform_kernel<32, 16, 1><<<nbN, TPB, 0, stream>>>(bufX, W3, as3, ad3, hH, asrc, adst, n);
  node_gat3<<<nbW3, TPB, 0, stream>>>(rowptr, csr_src, asrc, adst, hH, b3, Wout, bout, out, n);
}

// Round 20
// 345.447 us; speedup vs baseline: 1.0174x; 1.0174x over previous
//
#include <hip/hip_runtime.h>
#include <hip/hip_fp16.h>
#include <math.h>

#define TPB 256
#define PMAX 128       // max partitions
#define PSH 10         // partition = dst >> 10 (1024 nodes/partition; n <= 131072)
#define PW  1024       // nodes per partition
#define CHUNK 2048     // edges per block in scatter; KPT = CHUNK/TPB = 8
#define KPT 8
#define PCAP 38912     // per-partition staging cap (mean ~33.8K, sigma ~180 -> +28 sigma)
#define PCSTR 16       // pcursor stride: 1 counter per 64B cache line

__device__ __forceinline__ float leaky02(float x) { return x > 0.f ? x : 0.2f * x; }
__device__ __forceinline__ float eluf(float x) { return x > 0.f ? x : (__expf(x) - 1.f); }

// ====================== CSR build (direct-write scatter -> finalize w/ inline scan) ======================

__global__ __launch_bounds__(256) void scatter_kernel(const int* __restrict__ src,
                                                      const int* __restrict__ dst,
                                                      int E, int n,
                                                      int* __restrict__ pcursor,
                                                      unsigned* __restrict__ pstage) {
  __shared__ int lcnt[4][PMAX];    // per-wave counts -> per-wave cursors
  __shared__ int lbase[PMAX];      // global base (pcursor)
  int t = threadIdx.x;
  int wid = t >> 6;
  int Etot = E + n;
  int c0 = blockIdx.x * CHUNK;
  if (c0 >= Etot) return;
  int c1 = min(c0 + CHUNK, Etot);
  for (int j = t; j < 4 * PMAX; j += TPB) ((int*)lcnt)[j] = 0;

  int dd[KPT], ss[KPT];
  bool vv[KPT];
#pragma unroll
  for (int k = 0; k < KPT; ++k) {
    int idx = c0 + t + k * TPB;
    vv[k] = idx < c1;
    if (vv[k]) {
      if (idx < E) { ss[k] = src[idx]; dd[k] = dst[idx]; }
      else         { ss[k] = dd[k] = idx - E; }
    } else { ss[k] = 0; dd[k] = 0; }
  }
  __syncthreads();
#pragma unroll
  for (int k = 0; k < KPT; ++k)
    if (vv[k]) atomicAdd(&lcnt[wid][dd[k] >> PSH], 1);
  __syncthreads();
  if (t < PMAX) {
    int a0 = lcnt[0][t], a1 = lcnt[1][t], a2 = lcnt[2][t], a3 = lcnt[3][t];
    int tot = a0 + a1 + a2 + a3;
    lcnt[0][t] = 0; lcnt[1][t] = a0; lcnt[2][t] = a0 + a1; lcnt[3][t] = a0 + a1 + a2;
    lbase[t] = tot ? atomicAdd(&pcursor[t * PCSTR], tot) : 0;
  }
  __syncthreads();
#pragma unroll
  for (int k = 0; k < KPT; ++k) {
    if (vv[k]) {
      int p = dd[k] >> PSH;
      int sub = atomicAdd(&lcnt[wid][p], 1);   // starts at wave's exclusive offset
      pstage[(size_t)p * PCAP + lbase[p] + sub] =
          ((unsigned)ss[k] << PSH) | (unsigned)(dd[k] & (PW - 1));
    }
  }
}

// One 1024-thread block per partition. Inline 128-wide scan of padded pcursor
// totals; shfl-based node scan; streaming passes batched x4.
__global__ __launch_bounds__(1024) void build_csr_kernel(const unsigned* __restrict__ pstage,
                                                         const int* __restrict__ pcursor,
                                                         int nvtx,
                                                         int* __restrict__ rowptr,
                                                         int* __restrict__ csr_src) {
  __shared__ int ssum[PMAX];
  __shared__ int lhist[PW];
  __shared__ int lcur[PW];
  int t = threadIdx.x;
  int lane = t & 63;
  int wid = t >> 6;
  int p = blockIdx.x;
  size_t rbase = (size_t)p * PCAP;
  if (t < PMAX) ssum[t] = pcursor[t * PCSTR];
  lhist[t] = 0;
  __syncthreads();
  for (int off = 1; off < PMAX; off <<= 1) {
    int a = 0;
    if (t < PMAX && t >= off) a = ssum[t - off];
    __syncthreads();
    if (t < PMAX) ssum[t] += a;
    __syncthreads();
  }
  int cnt = pcursor[p * PCSTR];
  int wbase = ssum[p] - cnt;          // exclusive prefix for this partition
  int nodebase = p << PSH;
  for (int i = t; i < cnt; i += 4096) {
    unsigned w[4]; bool vv[4];
#pragma unroll
    for (int k = 0; k < 4; ++k) {
      int j = i + k * 1024;
      vv[k] = j < cnt;
      w[k] = vv[k] ? pstage[rbase + j] : 0u;
    }
#pragma unroll
    for (int k = 0; k < 4; ++k)
      if (vv[k]) atomicAdd(&lhist[w[k] & (PW - 1)], 1);
  }
  __syncthreads();
  int v = lhist[t];
  int x = v;
#pragma unroll
  for (int off = 1; off < 64; off <<= 1) {
    int u = __shfl_up(x, off);
    if (lane >= off) x += u;
  }
  if (lane == 63) lcur[wid] = x;       // wave sums in lcur[0..15]
  __syncthreads();
  if (t < 16) {
    int wsum = lcur[t];
    int y = wsum;
#pragma unroll
    for (int off = 1; off < 16; off <<= 1) {
      int u = __shfl_up(y, off);
      if (t >= off) y += u;
    }
    lcur[t] = y - wsum;                // exclusive wave offsets
  }
  __syncthreads();
  int acc = wbase + x + lcur[wid] - v; // exclusive start position of node t
  __syncthreads();
  lcur[t] = acc;
  int node = nodebase + t;
  if (node < nvtx) rowptr[node] = acc;
  __syncthreads();
  for (int i = t; i < cnt; i += 4096) {
    unsigned w[4]; bool vv[4];
#pragma unroll
    for (int k = 0; k < 4; ++k) {
      int j = i + k * 1024;
      vv[k] = j < cnt;
      w[k] = vv[k] ? pstage[rbase + j] : 0u;
    }
#pragma unroll
    for (int k = 0; k < 4; ++k) {
      if (vv[k]) {
        int pos = atomicAdd(&lcur[w[k] & (PW - 1)], 1);
        csr_src[pos] = (int)(w[k] >> PSH);
      }
    }
  }
  if (p == (int)gridDim.x - 1 && t == 0) rowptr[nvtx] = wbase + cnt;
}

// ====================== node transform (h = x@W fp32 -> stored fp16, attn logits fp32) ======================

template<int IN, int OUT, int H>
__global__ void transform_kernel(const float* __restrict__ x, const float* __restrict__ W,
                                 const float* __restrict__ a_src, const float* __restrict__ a_dst,
                                 __half* __restrict__ h, float* __restrict__ asrc,
                                 float* __restrict__ adst, int n) {
  __shared__ float sW[IN * OUT];
  __shared__ float sa[2 * OUT];
  for (int i = threadIdx.x; i < IN * OUT; i += blockDim.x) sW[i] = W[i];
  if (threadIdx.x < OUT) {
    sa[threadIdx.x] = a_src[threadIdx.x];
    sa[OUT + threadIdx.x] = a_dst[threadIdx.x];
  }
  __syncthreads();
  int i = blockIdx.x * blockDim.x + threadIdx.x;
  if (i >= n) return;
  float xv[IN];
#pragma unroll
  for (int k = 0; k < IN; k++) xv[k] = x[(size_t)i * IN + k];
  float hv[OUT];
#pragma unroll
  for (int j = 0; j < OUT; j++) {
    float acc = 0.f;
#pragma unroll
    for (int k = 0; k < IN; k++) acc += xv[k] * sW[k * OUT + j];
    hv[j] = acc;
  }
#pragma unroll
  for (int j = 0; j < OUT; j += 2)
    ((__half2*)h)[((size_t)i * OUT + j) >> 1] = __floats2half2_rn(hv[j], hv[j + 1]);
#pragma unroll
  for (int hh = 0; hh < H; hh++) {
    float as = 0.f, ad = 0.f;
#pragma unroll
    for (int c = 0; c < 16; c++) {
      as += hv[hh * 16 + c] * sa[hh * 16 + c];
      ad += hv[hh * 16 + c] * sa[OUT + hh * 16 + c];
    }
    asrc[i * H + hh] = as;
    adst[i * H + hh] = ad;
  }
}

// ====================== per-node GAT aggregation (2 nodes / wave, 32 lanes each) ======================
// No-max softmax (shift-invariant; R6-verified absmax unchanged). fp16 features.
// 2-node wave packing (R18-verified best: 1-node 52.6us, 2-node 49.5, 4-node 50.7):
// two independent front-end+gather streams per wave; 4 edge groups of 8 lanes,
// tiered depth NIT = ceil(cnt/4) <= 8. LDS half-window fully rewritten per chunk
// so any NIT >= ceil(cnt/4) is exact (R3-invariant). All shfl widths <= 32.

template<int NIT>
__device__ __forceinline__ void gat12_gather(const float2* __restrict__ sp,
                                             const uint2* __restrict__ hfp,
                                             int q, int g, float4& acc) {
  float2 p[NIT];
#pragma unroll
  for (int it = 0; it < NIT; ++it) p[it] = sp[2 * (g + it * 4)];
  uint2 hv[NIT];
#pragma unroll
  for (int it = 0; it < NIT; ++it) hv[it] = hfp[__float_as_int(p[it].x) + q];
#pragma unroll
  for (int it = 0; it < NIT; ++it) {
    float2 fa = __half22float2(*(const __half2*)&hv[it].x);
    float2 fb = __half22float2(*(const __half2*)&hv[it].y);
    float w = p[it].y;
    acc.x += w * fa.x; acc.y += w * fa.y;
    acc.z += w * fb.x; acc.w += w * fb.y;
  }
}

__device__ __forceinline__ void gat12_gather_t(const float2* sp, const uint2* hfp,
                                               int q, int g, int cnt, float4& acc) {
  switch ((cnt + 3) >> 2) {
    case 1: gat12_gather<1>(sp, hfp, q, g, acc); break;
    case 2: gat12_gather<2>(sp, hfp, q, g, acc); break;
    case 3: gat12_gather<3>(sp, hfp, q, g, acc); break;
    case 4: gat12_gather<4>(sp, hfp, q, g, acc); break;
    case 5: gat12_gather<5>(sp, hfp, q, g, acc); break;
    case 6: gat12_gather<6>(sp, hfp, q, g, acc); break;
    case 7: gat12_gather<7>(sp, hfp, q, g, acc); break;
    default: gat12_gather<8>(sp, hfp, q, g, acc); break;
  }
}

__global__ __launch_bounds__(256) void node_gat12(
    const int* __restrict__ rowptr,
    const int* __restrict__ csr_src,
    const float* __restrict__ asrc,  // [n*2] fp32
    const float* __restrict__ adst,  // [n*2] fp32
    const __half* __restrict__ hfeat,// [n*32] fp16
    const float* __restrict__ bias,  // [32]
    float* __restrict__ outb,        // [n*32] fp32
    int n) {
  __shared__ float4 s_e[4][64];    // (sidx<<3, w0, sidx<<3, w1); 32-entry window per half
  int t = threadIdx.x;
  int wid = t >> 6;
  int sub = t & 31;
  int half = (t >> 5) & 1;
  int i = (blockIdx.x * TPB + t) >> 5;   // 2 nodes per wave
  if (i >= n) return;
  int start = rowptr[i];
  int d = rowptr[i + 1] - start;
  float ad0 = adst[i * 2 + 0];
  float ad1 = adst[i * 2 + 1];
  const uint2* hfp = (const uint2*)hfeat;   // 8B chunks; 8 per 32-ch row
  const float2* asrc2 = (const float2*)asrc;
  int g = sub >> 3;    // edge group 0..3
  int q = sub & 7;     // chunk slot (q<4: head0, q>=4: head1)
  const float2* sp = (const float2*)(&s_e[wid][half * 32]) + (q >> 2);
  float4 acc = make_float4(0.f, 0.f, 0.f, 0.f);
  float sl0 = 0.f, sl1 = 0.f;

  for (int base = 0; base < d; base += 32) {
    int k = base + sub;
    int sidx8 = 0;
    float w0 = 0.f, w1 = 0.f;
    if (k < d) {
      int sidx = csr_src[start + k];
      sidx8 = sidx << 3;
      float2 av = asrc2[sidx];
      w0 = __expf(leaky02(av.x + ad0));
      w1 = __expf(leaky02(av.y + ad1));
      sl0 += w0; sl1 += w1;
    }
    s_e[wid][half * 32 + sub] = make_float4(__int_as_float(sidx8), w0,
                                            __int_as_float(sidx8), w1);
    // same-wave LDS write->read ordering (R4-verified); tiered gather
    int cnt = min(32, d - base);
    gat12_gather_t(sp, hfp, q, g, cnt, acc);
  }

#pragma unroll
  for (int off = 16; off >= 1; off >>= 1) {
    sl0 += __shfl_xor(sl0, off);
    sl1 += __shfl_xor(sl1, off);
  }
  // reduce over 4 edge groups (g = sub>>3): xor 8 then 16 stays within the half
  acc.x += __shfl_xor(acc.x, 8);  acc.y += __shfl_xor(acc.y, 8);
  acc.z += __shfl_xor(acc.z, 8);  acc.w += __shfl_xor(acc.w, 8);
  acc.x += __shfl_xor(acc.x, 16); acc.y += __shfl_xor(acc.y, 16);
  acc.z += __shfl_xor(acc.z, 16); acc.w += __shfl_xor(acc.w, 16);
  if (sub < 8) {
    float inv = 1.f / (((sub >= 4) ? sl1 : sl0) + 1e-16f);
    float4 bv = ((const float4*)bias)[sub];
    float4 o;
    o.x = eluf(acc.x * inv + bv.x);
    o.y = eluf(acc.y * inv + bv.y);
    o.z = eluf(acc.z * inv + bv.z);
    o.w = eluf(acc.w * inv + bv.w);
    ((float4*)outb)[(size_t)i * 8 + sub] = o;
  }
}

// gat3: 2 nodes/wave, 4B (half2) loads; 4 edge groups of 8 lanes (channels 2q,2q+1).
template<int NIT>
__device__ __forceinline__ void gat3_gather(const float2* __restrict__ sp,
                                            const unsigned* __restrict__ hfp,
                                            int q, int g, float2& acc) {
  float2 p[NIT];
#pragma unroll
  for (int it = 0; it < NIT; ++it) p[it] = sp[g + it * 4];
  unsigned hv[NIT];
#pragma unroll
  for (int it = 0; it < NIT; ++it) hv[it] = hfp[__float_as_int(p[it].x) + q];
#pragma unroll
  for (int it = 0; it < NIT; ++it) {
    float2 f = __half22float2(*(const __half2*)&hv[it]);
    float w = p[it].y;
    acc.x += w * f.x; acc.y += w * f.y;
  }
}

__device__ __forceinline__ void gat3_gather_t(const float2* sp, const unsigned* hfp,
                                              int q, int g, int cnt, float2& acc) {
  switch ((cnt + 3) >> 2) {
    case 1: gat3_gather<1>(sp, hfp, q, g, acc); break;
    case 2: gat3_gather<2>(sp, hfp, q, g, acc); break;
    case 3: gat3_gather<3>(sp, hfp, q, g, acc); break;
    case 4: gat3_gather<4>(sp, hfp, q, g, acc); break;
    case 5: gat3_gather<5>(sp, hfp, q, g, acc); break;
    case 6: gat3_gather<6>(sp, hfp, q, g, acc); break;
    case 7: gat3_gather<7>(sp, hfp, q, g, acc); break;
    default: gat3_gather<8>(sp, hfp, q, g, acc); break;
  }
}

__global__ __launch_bounds__(256) void node_gat3(
    const int* __restrict__ rowptr,
    const int* __restrict__ csr_src,
    const float* __restrict__ asrc,  // [n] fp32
    const float* __restrict__ adst,  // [n] fp32
    const __half* __restrict__ hfeat,// [n*16] fp16
    const float* __restrict__ b3,    // [16]
    const float* __restrict__ Wout,  // [16]
    const float* __restrict__ bout,  // [1]
    float* __restrict__ out,         // [n] sigmoid ++ [n*16] embeddings (fp32)
    int n) {
  __shared__ float2 s_hw[4][64];   // (sidx<<3, w); 32-entry window per half
  int t = threadIdx.x;
  int wid = t >> 6;
  int sub = t & 31;
  int half = (t >> 5) & 1;
  int i = (blockIdx.x * TPB + t) >> 5;   // 2 nodes per wave
  if (i >= n) return;
  int start = rowptr[i];
  int d = rowptr[i + 1] - start;
  float ad0 = adst[i];
  const unsigned* hfp = (const unsigned*)hfeat;   // 4B chunks; 8 per 16-ch row
  int g = sub >> 3;    // edge group 0..3
  int q = sub & 7;     // half2 chunk slot (channels 2q, 2q+1)
  const float2* sp = &s_hw[wid][half * 32];
  float2 acc = make_float2(0.f, 0.f);
  float sl = 0.f;

  for (int base = 0; base < d; base += 32) {
    int k = base + sub;
    int sidx8 = 0;
    float w0 = 0.f;
    if (k < d) {
      int sidx = csr_src[start + k];
      sidx8 = sidx << 3;
      w0 = __expf(leaky02(asrc[sidx] + ad0));
      sl += w0;
    }
    s_hw[wid][half * 32 + sub] = make_float2(__int_as_float(sidx8), w0);
    int cnt = min(32, d - base);
    gat3_gather_t(sp, hfp, q, g, cnt, acc);
  }

#pragma unroll
  for (int off = 16; off >= 1; off >>= 1) sl += __shfl_xor(sl, off);
  acc.x += __shfl_xor(acc.x, 8);  acc.y += __shfl_xor(acc.y, 8);
  acc.x += __shfl_xor(acc.x, 16); acc.y += __shfl_xor(acc.y, 16);
  float z = 0.f;
  if (sub < 8) {
    float inv = 1.f / (sl + 1e-16f);
    float2 bv = ((const float2*)b3)[sub];
    float2 wv = ((const float2*)Wout)[sub];
    float2 o;
    o.x = eluf(acc.x * inv + bv.x);
    o.y = eluf(acc.y * inv + bv.y);
    ((float2*)(out + n))[(size_t)i * 8 + sub] = o;
    z = o.x * wv.x + o.y * wv.y;
  }
  z += __shfl_xor(z, 1);
  z += __shfl_xor(z, 2);
  z += __shfl_xor(z, 4);
  if (sub == 0) out[i] = 1.f / (1.f + __expf(-(z + bout[0])));
}

// ====================== launch ======================

extern "C" void kernel_launch(void* const* d_in, const int* in_sizes, int n_in,
                              void* d_out, int out_size, void* d_ws, size_t ws_size,
                              hipStream_t stream) {
  const float* x    = (const float*)d_in[0];
  const int*   ei   = (const int*)d_in[1];
  const float* W1   = (const float*)d_in[2];
  const float* as1  = (const float*)d_in[3];
  const float* ad1  = (const float*)d_in[4];
  const float* b1   = (const float*)d_in[5];
  const float* W2   = (const float*)d_in[6];
  const float* as2  = (const float*)d_in[7];
  const float* ad2  = (const float*)d_in[8];
  const float* b2   = (const float*)d_in[9];
  const float* W3   = (const float*)d_in[10];
  const float* as3  = (const float*)d_in[11];
  const float* ad3  = (const float*)d_in[12];
  const float* b3   = (const float*)d_in[13];
  const float* Wout = (const float*)d_in[14];
  const float* bout = (const float*)d_in[15];
  float* out = (float*)d_out;

  const int n = in_sizes[0] / 3;
  const int E = in_sizes[1] / 2;
  const int Etot = E + n;
  const int* src = ei;
  const int* dst = ei + E;
  const int nbC = (Etot + CHUNK - 1) / CHUNK;
  const int NP = ((n - 1) >> PSH) + 1;   // n=100000 -> 98 partitions

  float* ws = (float*)d_ws;
  float* bufH = ws;                               // n*32 floats (h stored as n*32 halves)
  float* bufX = bufH + (size_t)n * 32;            // n*32 fp32 (gat output / next-layer x)
  float* asrc = bufX + (size_t)n * 32;            // n*2
  float* adst = asrc + (size_t)n * 2;             // n*2
  int* rowptr  = (int*)(adst + (size_t)n * 2);    // n+1
  int* pcursor = rowptr + n + 1;                  // PMAX*PCSTR (8KB, padded)
  int* csr_src = pcursor + PMAX * PCSTR;          // Etot
  unsigned* pstage = (unsigned*)ws;               // PMAX*PCAP (~19.9MB) aliases bufH+bufX; dead before transforms
  __half* hH = (__half*)bufH;

  const int nbN = (n + TPB - 1) / TPB;
  const int nbW = (n + 7) / 8;                    // 2 nodes per wave, 8 per block

  // ---- CSR build ----
  hipMemsetAsync(pcursor, 0, PMAX * PCSTR * sizeof(int), stream);
  scatter_kernel<<<nbC, TPB, 0, stream>>>(src, dst, E, n, pcursor, pstage);
  build_csr_kernel<<<NP, 1024, 0, stream>>>(pstage, pcursor, n, rowptr, csr_src);

  // ---- layer 1: in=3, out=32, H=2 ----
  transform_kernel<3, 32, 2><<<nbN, TPB, 0, stream>>>(x, W1, as1, ad1, hH, asrc, adst, n);
  node_gat12<<<nbW, TPB, 0, stream>>>(rowptr, csr_src, asrc, adst, hH, b1, bufX, n);

  // ---- layer 2: in=32, out=32, H=2 ----
  transform_kernel<32, 32, 2><<<nbN, TPB, 0, stream>>>(bufX, W2, as2, ad2, hH, asrc, adst, n);
  node_gat12<<<nbW, TPB, 0, stream>>>(rowptr, csr_src, asrc, adst, hH, b2, bufX, n);

  // ---- layer 3: in=32, out=16, H=1 ----
  transform_kernel<32, 16, 1><<<nbN, TPB, 0, stream>>>(bufX, W3, as3, ad3, hH, asrc, adst, n);
  node_gat3<<<nbW, TPB, 0, stream>>>(rowptr, csr_src, asrc, adst, hH, b3, Wout, bout, out, n);
}